// Round 7
// baseline (3508.068 us; speedup 1.0000x reference)
//
#include <hip/hip_runtime.h>

#define NB 16
#define NN 8192
#define NS 1024
#define NK 32
#define NR (NB*NS*NK)   // 524288 rows through the MLP

static __device__ __forceinline__ int brev6(int l) {
  return ((l&1)<<5)|((l&2)<<3)|((l&4)<<1)|((l&8)>>1)|((l&16)>>3)|((l&32)>>5);
}
static __device__ __forceinline__ int brev5(int l) {
  return ((l&1)<<4)|((l&2)<<2)|(l&4)|((l&8)>>2)|((l&16)>>4);
}

// pack two f32 -> two bf16 (RNE) in one uint (low = first)
static __device__ __forceinline__ unsigned pack_bf2(float a, float b) {
  unsigned ua = __float_as_uint(a), ub = __float_as_uint(b);
  ua += 0x7fffu + ((ua >> 16) & 1u);
  ub += 0x7fffu + ((ub >> 16) & 1u);
  return (ua >> 16) | (ub & 0xffff0000u);
}
static __device__ __forceinline__ float bf_lo(unsigned u) { return __uint_as_float(u << 16); }
static __device__ __forceinline__ float bf_hi(unsigned u) { return __uint_as_float(u & 0xffff0000u); }

// ---------------------------------------------------------------------------
// FPS v3: one block (512 thr = 8 waves, 2/SIMD) per batch, 16 pts/thread.
// xyz batch mirrored in LDS (96 KB) -> per-step centroid broadcast is an LDS
// read, not an L2 round-trip. One barrier/step, parity-buffered wave keys.
// Exact f32 arithmetic (no fma, ascending) + first-index tie-break: decisions
// bit-identical to the passing version. DO NOT change the math.
// ---------------------------------------------------------------------------
__global__ __launch_bounds__(512, 1) void fps_kernel(const float* __restrict__ xyz,
                                                     float* __restrict__ new_xyz) {
  const int b = blockIdx.x;
  const int t = threadIdx.x;        // 0..511
  const int lane = t & 63;
  const int wv = t >> 6;            // 0..7
  const float* base = xyz + (size_t)b * NN * 3;

  __shared__ float sx[NN], sy[NN], sz[NN];    // 96 KB mirror
  __shared__ unsigned long long s_wb[2][8];   // [parity][wave]

  float px[16], py[16], pz[16], dist[16];
#pragma unroll
  for (int j = 0; j < 16; ++j) {
    int p = j * 512 + t;
    float x = base[p*3+0], y = base[p*3+1], z = base[p*3+2];
    px[j] = x; py[j] = y; pz[j] = z; dist[j] = 1e10f;
    sx[p] = x; sy[p] = y; sz[p] = z;
  }
  __syncthreads();

  float cx = sx[0], cy = sy[0], cz = sz[0];
  float* outp = new_xyz + (size_t)b * NS * 3;
  if (t == 0) { outp[0] = cx; outp[1] = cy; outp[2] = cz; }

  for (int s = 1; s < NS; ++s) {
    const int par = s & 1;
    float bestv = -1.0f; int besti = 0;
#pragma unroll
    for (int j = 0; j < 16; ++j) {
      float dx = px[j]-cx, dy = py[j]-cy, dz = pz[j]-cz;
      // exact numpy order: (dx*dx + dy*dy) + dz*dz, no contraction
      float d = __fadd_rn(__fadd_rn(__fmul_rn(dx,dx),__fmul_rn(dy,dy)),__fmul_rn(dz,dz));
      float nd = fminf(dist[j], d);
      dist[j] = nd;
      if (nd > bestv) { bestv = nd; besti = j*512 + t; }
    }
    // key: larger dist wins; on tie, smaller index wins (8191-idx larger)
    unsigned long long key =
        ((unsigned long long)__float_as_uint(bestv) << 32) | (unsigned)(8191 - besti);
#pragma unroll
    for (int off = 32; off >= 1; off >>= 1) {
      unsigned long long o2 = __shfl_xor(key, off, 64);
      if (o2 > key) key = o2;
    }
    if (lane == 0) s_wb[par][wv] = key;
    __syncthreads();                           // the only barrier per step
    unsigned long long gk = s_wb[par][0];
#pragma unroll
    for (int i = 1; i < 8; ++i) {
      unsigned long long ki = s_wb[par][i]; if (ki > gk) gk = ki;
    }
    const int bi = 8191 - (int)(gk & 0xffffull);
    cx = sx[bi]; cy = sy[bi]; cz = sz[bi];     // LDS broadcast, ~120 cyc
    if (t == 0) {
      float* o = outp + s*3;
      o[0] = cx; o[1] = cy; o[2] = cz;
    }
  }
}

// ---------------------------------------------------------------------------
// Ball query + gather + concat: one wave per (b,s) query. PASSES — unchanged.
// dt = ascending FMA chain (BLAS K=3 microkernel), t1/t2 ascending no-fma.
// ---------------------------------------------------------------------------
__global__ __launch_bounds__(256) void ballquery_kernel(const float* __restrict__ xyz,
                                                        const float* __restrict__ pts,
                                                        const float* __restrict__ new_xyz,
                                                        float* __restrict__ x0) {
  const int gw = ((blockIdx.x << 8) + threadIdx.x) >> 6;
  const int lane = threadIdx.x & 63;
  const int b = gw >> 10;
  const float* base = xyz + (size_t)b * NN * 3;
  const float* pbase = pts + (size_t)b * NN * 3;
  const float* cp = new_xyz + (size_t)gw * 3;
  const float cx = cp[0], cy = cp[1], cz = cp[2];
  const float t1 = __fadd_rn(__fadd_rn(__fmul_rn(cx,cx),__fmul_rn(cy,cy)),__fmul_rn(cz,cz));
  const float R2 = 0.04f;
  float* out = x0 + (size_t)gw * (NK*6);

  int count = 0, pfirst = 0;
  for (int n0 = 0; n0 < NN; n0 += 64) {
    const int p = n0 + lane;
    const float ax = base[p*3], ay = base[p*3+1], az = base[p*3+2];
    const float t2 = __fadd_rn(__fadd_rn(__fmul_rn(ax,ax),__fmul_rn(ay,ay)),__fmul_rn(az,az));
    const float dt = __fmaf_rn(cz, az, __fmaf_rn(cy, ay, __fmul_rn(cx, ax)));
    const float sq = __fadd_rn(__fsub_rn(t1, __fmul_rn(2.0f,dt)), t2);
    const bool keep = !(sq > R2);
    const unsigned long long mask = __ballot(keep);
    const int slot = count + __popcll(mask & ((1ull<<lane)-1ull));
    if (keep && slot < NK) {
      float* o = out + slot*6;
      o[0]=ax-cx; o[1]=ay-cy; o[2]=az-cz;
      o[3]=pbase[p*3]; o[4]=pbase[p*3+1]; o[5]=pbase[p*3+2];
    }
    if (count == 0 && mask != 0ull) pfirst = n0 + (__ffsll((unsigned long long)mask) - 1);
    count += __popcll(mask);
    if (count >= NK) break;
  }
  if (count < NK) {
    const float* fx = base + (size_t)pfirst*3;
    const float* fp = pbase + (size_t)pfirst*3;
    const float a0 = fx[0]-cx, a1 = fx[1]-cy, a2 = fx[2]-cz;
    const float a3 = fp[0], a4 = fp[1], a5 = fp[2];
    for (int sl = count + lane; sl < NK; sl += 64) {
      float* o = out + sl*6;
      o[0]=a0;o[1]=a1;o[2]=a2;o[3]=a3;o[4]=a4;o[5]=a5;
    }
  }
}

// ---------------------------------------------------------------------------
// Wave transpose-reduces.
// butterfly64: z[0] = sum over 64 lanes of channel brev6(lane)  (64 regs)
// foldsum32:   z[0] = sum over 64 lanes of channel brev5(lane&31) (32 regs;
//              pre-fold over xor-32, then 5-level butterfly)
// ---------------------------------------------------------------------------
__device__ __forceinline__ void butterfly64(float (&z)[64], float (&q)[64], int lane) {
#pragma unroll
  for (int d = 0; d < 6; ++d) {
    const int m = 32 >> d;
    const bool hi = (lane >> d) & 1;
#pragma unroll
    for (int i = 0; i < m; ++i) {
      float sv = hi ? z[i] : z[i+m];
      float rv = __shfl_xor(sv, 1<<d, 64);
      z[i] = (hi ? z[i+m] : z[i]) + rv;
      float sq = hi ? q[i] : q[i+m];
      float rq = __shfl_xor(sq, 1<<d, 64);
      q[i] = (hi ? q[i+m] : q[i]) + rq;
    }
  }
}

__device__ __forceinline__ void foldsum32(float (&z)[32], float (&q)[32], int lane) {
#pragma unroll
  for (int i = 0; i < 32; ++i) {
    z[i] += __shfl_xor(z[i], 32, 64);
    q[i] += __shfl_xor(q[i], 32, 64);
  }
#pragma unroll
  for (int d = 0; d < 5; ++d) {
    const int m = 16 >> d;
    const bool hi = (lane >> d) & 1;
#pragma unroll
    for (int i = 0; i < m; ++i) {
      float sv = hi ? z[i] : z[i+m];
      float rv = __shfl_xor(sv, 1<<d, 64);
      z[i] = (hi ? z[i+m] : z[i]) + rv;
      float sq = hi ? q[i] : q[i+m];
      float rq = __shfl_xor(sq, 1<<d, 64);
      q[i] = (hi ? q[i+m] : q[i]) + rq;
    }
  }
}

// ---------------------------------------------------------------------------
// BN finalize: reduce per-wave partials in f64, emit scale/shift per channel.
// ---------------------------------------------------------------------------
__global__ __launch_bounds__(256) void finalize_kernel(const float* __restrict__ part,
                                                       int nrows, int rowstride, int C,
                                                       const float* __restrict__ g,
                                                       const float* __restrict__ be,
                                                       float* __restrict__ ab) {
  const int ch = blockIdx.x;
  const int t = threadIdx.x;
  const int qo = rowstride >> 1;
  double s = 0.0, q = 0.0;
  for (int wv = t; wv < nrows; wv += 256) {
    s += (double)part[(size_t)wv*rowstride + ch];
    q += (double)part[(size_t)wv*rowstride + qo + ch];
  }
#pragma unroll
  for (int off = 32; off >= 1; off >>= 1) {
    s += __shfl_down(s, off, 64);
    q += __shfl_down(q, off, 64);
  }
  __shared__ double ls[4], lq[4];
  if ((t & 63) == 0) { ls[t>>6] = s; lq[t>>6] = q; }
  __syncthreads();
  if (t == 0) {
    double S = ls[0]+ls[1]+ls[2]+ls[3];
    double Q = lq[0]+lq[1]+lq[2]+lq[3];
    double mean = S / (double)NR;
    double var  = Q / (double)NR - mean*mean;
    double inv  = 1.0 / sqrt(var + 1e-5);
    double gg   = (double)g[ch];
    ab[ch]     = (float)(gg * inv);
    ab[C + ch] = (float)((double)be[ch] - mean * gg * inv);
  }
}

// ============================ MLP passes ============================

__global__ __launch_bounds__(256) void stats1_kernel(const float* __restrict__ x0,
                                                     const float* __restrict__ w,
                                                     const float* __restrict__ bias,
                                                     float* __restrict__ part) {
  const int r = blockIdx.x * 256 + threadIdx.x;
  const int lane = threadIdx.x & 63;
  const float* xr = x0 + (size_t)r * 6;
  float x[6];
#pragma unroll
  for (int c = 0; c < 6; ++c) x[c] = xr[c];
  float z[64];
#pragma unroll
  for (int o = 0; o < 64; ++o) {
    float acc = bias[o];
#pragma unroll
    for (int c = 0; c < 6; ++c) acc = fmaf(x[c], w[o*6+c], acc);
    z[o] = acc;
  }
  float q[64];
#pragma unroll
  for (int o = 0; o < 64; ++o) q[o] = z[o]*z[o];
  butterfly64(z, q, lane);
  const int gw = (blockIdx.x * 256 + threadIdx.x) >> 6;
  const int ch = brev6(lane);
  part[(size_t)gw*128 + ch]      = z[0];
  part[(size_t)gw*128 + 64 + ch] = q[0];
}

__device__ __forceinline__ void lean_h1(const float* __restrict__ xr,
                                        const float* __restrict__ w1,
                                        const float* __restrict__ b1,
                                        const float* __restrict__ ab1,
                                        float (&h)[64]) {
  float x[6];
#pragma unroll
  for (int c = 0; c < 6; ++c) x[c] = xr[c];
#pragma unroll
  for (int o = 0; o < 64; ++o) {
    float acc = b1[o];
#pragma unroll
    for (int c = 0; c < 6; ++c) acc = fmaf(x[c], w1[o*6+c], acc);
    h[o] = fmaxf(0.f, fmaf(acc, ab1[o], ab1[64+o]));
  }
}

// Pass 2: recompute h1, z2 = layer2, store z2 bf16, partial sums.
__global__ __launch_bounds__(256) void stats2_store(const float* __restrict__ x0,
                                                    const float* __restrict__ w1,
                                                    const float* __restrict__ b1,
                                                    const float* __restrict__ ab1,
                                                    const float* __restrict__ w2,
                                                    const float* __restrict__ b2,
                                                    unsigned* __restrict__ z2u,
                                                    float* __restrict__ part) {
  const int r = blockIdx.x * 256 + threadIdx.x;
  const int lane = threadIdx.x & 63;
  float h[64];
  lean_h1(x0 + (size_t)r*6, w1, b1, ab1, h);
  const int gw = r >> 6;
  const int ch5 = brev5(lane & 31);
#pragma unroll 1
  for (int chunk = 0; chunk < 2; ++chunk) {
    const int cbase = chunk * 32;
    float z[32];
#pragma unroll
    for (int o = 0; o < 32; ++o) {
      float acc = b2[cbase + o];
      const float* wr = w2 + (size_t)(cbase + o) * 64;
#pragma unroll
      for (int c = 0; c < 64; ++c) acc = fmaf(h[c], wr[c], acc);
      z[o] = acc;
    }
    uint4* zw = (uint4*)(z2u + (size_t)r * 32 + chunk*16);
#pragma unroll
    for (int i = 0; i < 4; ++i)
      zw[i] = make_uint4(pack_bf2(z[8*i+0],z[8*i+1]), pack_bf2(z[8*i+2],z[8*i+3]),
                         pack_bf2(z[8*i+4],z[8*i+5]), pack_bf2(z[8*i+6],z[8*i+7]));
    float q[32];
#pragma unroll
    for (int o = 0; o < 32; ++o) q[o] = z[o]*z[o];
    foldsum32(z, q, lane);
    if (lane < 32) {
      part[(size_t)gw*128 + cbase + ch5]      = z[0];
      part[(size_t)gw*128 + 64 + cbase + ch5] = q[0];
    }
  }
}

// Pass 3: read z2 bf16, bn2+relu, z3 = layer3 (4 chunks of 32 ch),
// partial sums + per-(b,s)-group max AND min over k (32 lanes = 32 rows).
// z3 never materialized.
__global__ __launch_bounds__(256) void stats3_kmax(const unsigned* __restrict__ z2u,
                                                   const float* __restrict__ ab2,
                                                   const float* __restrict__ w3,
                                                   const float* __restrict__ b3,
                                                   float* __restrict__ part,
                                                   float* __restrict__ kmx,
                                                   float* __restrict__ kmn) {
  const int r = blockIdx.x * 256 + threadIdx.x;
  const int lane = threadIdx.x & 63;
  const uint4* zr = (const uint4*)(z2u + (size_t)r * 32);
  float h[64];
#pragma unroll
  for (int i = 0; i < 8; ++i) {
    uint4 v = zr[i];
    const int c = i*8;
    h[c+0]=fmaxf(0.f,fmaf(bf_lo(v.x),ab2[c+0],ab2[64+c+0]));
    h[c+1]=fmaxf(0.f,fmaf(bf_hi(v.x),ab2[c+1],ab2[64+c+1]));
    h[c+2]=fmaxf(0.f,fmaf(bf_lo(v.y),ab2[c+2],ab2[64+c+2]));
    h[c+3]=fmaxf(0.f,fmaf(bf_hi(v.y),ab2[c+3],ab2[64+c+3]));
    h[c+4]=fmaxf(0.f,fmaf(bf_lo(v.z),ab2[c+4],ab2[64+c+4]));
    h[c+5]=fmaxf(0.f,fmaf(bf_hi(v.z),ab2[c+5],ab2[64+c+5]));
    h[c+6]=fmaxf(0.f,fmaf(bf_lo(v.w),ab2[c+6],ab2[64+c+6]));
    h[c+7]=fmaxf(0.f,fmaf(bf_hi(v.w),ab2[c+7],ab2[64+c+7]));
  }
  const int gw = r >> 6;
  const int group = gw*2 + (lane >> 5);     // (b,s) index, 2 per wave
  const int ch5 = brev5(lane & 31);
#pragma unroll 1
  for (int chunk = 0; chunk < 4; ++chunk) {
    const int cbase = chunk * 32;
    float z[32];
#pragma unroll
    for (int o = 0; o < 32; ++o) {
      float acc = b3[cbase + o];
      const float* wr = w3 + (size_t)(cbase + o) * 64;
#pragma unroll
      for (int c = 0; c < 64; ++c) acc = fmaf(h[c], wr[c], acc);
      z[o] = acc;
    }
    // k-max / k-min over the 32 lanes of this half-wave (one (b,s) group)
    {
      float mx[32], mn[32];
#pragma unroll
      for (int o = 0; o < 32; ++o) { mx[o] = z[o]; mn[o] = z[o]; }
#pragma unroll
      for (int off = 1; off <= 16; off <<= 1) {
#pragma unroll
        for (int o = 0; o < 32; ++o) {
          mx[o] = fmaxf(mx[o], __shfl_xor(mx[o], off, 64));
          mn[o] = fminf(mn[o], __shfl_xor(mn[o], off, 64));
        }
      }
      if ((lane & 31) == 0) {
        float* px = kmx + (size_t)group*128 + cbase;
        float* pn = kmn + (size_t)group*128 + cbase;
#pragma unroll
        for (int o = 0; o < 32; ++o) { px[o] = mx[o]; pn[o] = mn[o]; }
      }
    }
    float q[32];
#pragma unroll
    for (int o = 0; o < 32; ++o) q[o] = z[o]*z[o];
    foldsum32(z, q, lane);
    if (lane < 32) {
      part[(size_t)gw*256 + cbase + ch5]        = z[0];
      part[(size_t)gw*256 + 128 + cbase + ch5]  = q[0];
    }
  }
}

// bn3: out[g][c] = relu(a*sel + b), sel = a>=0 ? kmax : kmin  (max commutes
// with monotone affine+relu; sign of a picks the right extreme).
__global__ __launch_bounds__(128) void bn3_kernel(const float* __restrict__ kmx,
                                                  const float* __restrict__ kmn,
                                                  const float* __restrict__ ab,
                                                  float* __restrict__ outp) {
  const int g = blockIdx.x;
  const int c = threadIdx.x;
  const float a = ab[c], bsh = ab[128 + c];
  const float v = (a >= 0.f) ? kmx[(size_t)g*128 + c] : kmn[(size_t)g*128 + c];
  outp[(size_t)g*128 + c] = fmaxf(0.f, fmaf(v, a, bsh));
}

// ============================ launcher ============================

extern "C" void kernel_launch(void* const* d_in, const int* in_sizes, int n_in,
                              void* d_out, int out_size, void* d_ws, size_t ws_size,
                              hipStream_t stream) {
  (void)in_sizes; (void)n_in; (void)out_size; (void)ws_size;
  const float* xyz = (const float*)d_in[0];
  const float* pts = (const float*)d_in[1];
  const float* w1  = (const float*)d_in[2];
  const float* b1  = (const float*)d_in[3];
  const float* g1  = (const float*)d_in[4];
  const float* be1 = (const float*)d_in[5];
  const float* w2  = (const float*)d_in[6];
  const float* b2  = (const float*)d_in[7];
  const float* g2  = (const float*)d_in[8];
  const float* be2 = (const float*)d_in[9];
  const float* w3  = (const float*)d_in[10];
  const float* b3  = (const float*)d_in[11];
  const float* g3  = (const float*)d_in[12];
  const float* be3 = (const float*)d_in[13];

  float* out = (float*)d_out;
  float* new_xyz    = out;
  float* new_points = out + NB*NS*3;

  // workspace: x0 (12.6 MB) | part (8 MB) | ab (2 KB) | z2 bf16 (67 MB) |
  //            kmax/kmin (16 MB)  — total ~104 MB
  float* ws = (float*)d_ws;
  float* x0   = ws;                               // NR*6
  float* part = x0 + (size_t)NR*6;                // 2M floats
  float* ab   = part + 2097152;                   // 512
  float* ab1  = ab;
  float* ab2  = ab + 128;
  float* ab3  = ab + 256;
  unsigned* z2u = (unsigned*)(ab + 512);          // NR*32 u32
  float* kmx = (float*)(z2u + (size_t)NR*32);     // 16384*128
  float* kmn = kmx + (size_t)16384*128;           // 16384*128

  hipLaunchKernelGGL(fps_kernel, dim3(NB), dim3(512), 0, stream, xyz, new_xyz);
  hipLaunchKernelGGL(ballquery_kernel, dim3(NB*NS/4), dim3(256), 0, stream, xyz, pts, new_xyz, x0);

  hipLaunchKernelGGL(stats1_kernel, dim3(NR/256), dim3(256), 0, stream, x0, w1, b1, part);
  hipLaunchKernelGGL(finalize_kernel, dim3(64), dim3(256), 0, stream, part, NR/64, 128, 64, g1, be1, ab1);
  hipLaunchKernelGGL(stats2_store, dim3(NR/256), dim3(256), 0, stream,
                     x0, w1, b1, ab1, w2, b2, z2u, part);
  hipLaunchKernelGGL(finalize_kernel, dim3(64), dim3(256), 0, stream, part, NR/64, 128, 64, g2, be2, ab2);
  hipLaunchKernelGGL(stats3_kmax, dim3(NR/256), dim3(256), 0, stream,
                     z2u, ab2, w3, b3, part, kmx, kmn);
  hipLaunchKernelGGL(finalize_kernel, dim3(128), dim3(256), 0, stream, part, NR/64, 256, 128, g3, be3, ab3);
  hipLaunchKernelGGL(bn3_kernel, dim3(NB*NS), dim3(128), 0, stream, kmx, kmn, ab3, new_points);
}